// Round 15
// baseline (1001.900 us; speedup 1.0000x reference)
//
#include <hip/hip_runtime.h>
#include <cstdint>
#include <cstddef>

#define EPS_BN 1e-5f
#define CIS_CAP 640

typedef unsigned short ushort_t;
typedef _Float16 h8 __attribute__((ext_vector_type(8)));
typedef _Float16 h2 __attribute__((ext_vector_type(2)));
typedef __attribute__((ext_vector_type(4))) float f32x4;

static inline int idiv(int a, int b) { return (a + b - 1) / b; }

__device__ __forceinline__ float h2f(ushort_t b) {
  _Float16 h; __builtin_memcpy(&h, &b, 2); return (float)h;
}
__device__ __forceinline__ ushort_t f2h(float x) {
  _Float16 h = (_Float16)x; ushort_t b; __builtin_memcpy(&b, &h, 2); return b;
}
__device__ __forceinline__ float hlo(unsigned u) { return h2f((ushort_t)(u & 0xffffu)); }
__device__ __forceinline__ float hhi(unsigned u) { return h2f((ushort_t)(u >> 16)); }
__device__ __forceinline__ int imin(int a, int b) { return a < b ? a : b; }

// ---------------- CSR build ----------------
__global__ void cnt_kernel(const int* __restrict__ ei, int* __restrict__ cnt, int E) {
  int e = blockIdx.x * 256 + threadIdx.x;
  if (e < E) atomicAdd(&cnt[ei[E + e]], 1);
}

#define SCAN_TPB 256
#define SCAN_EPT 16
#define SCAN_EPB (SCAN_TPB * SCAN_EPT)

__global__ __launch_bounds__(SCAN_TPB) void bsum_kernel(const int* __restrict__ cnt,
                                                        int* __restrict__ bsum, int n) {
  __shared__ int sm[SCAN_TPB];
  int lo = blockIdx.x * SCAN_EPB + threadIdx.x * SCAN_EPT;
  int s = 0;
#pragma unroll
  for (int i = 0; i < SCAN_EPT; ++i) { int idx = lo + i; if (idx < n) s += cnt[idx]; }
  sm[threadIdx.x] = s;
  __syncthreads();
  for (int off = SCAN_TPB / 2; off; off >>= 1) {
    if (threadIdx.x < off) sm[threadIdx.x] += sm[threadIdx.x + off];
    __syncthreads();
  }
  if (threadIdx.x == 0) bsum[blockIdx.x] = sm[0];
}

__global__ __launch_bounds__(1024) void bscan_kernel(int* __restrict__ bsum, int nb) {
  __shared__ int sm[1024];
  int t = threadIdx.x;
  int v = (t < nb) ? bsum[t] : 0;
  sm[t] = v;
  __syncthreads();
  for (int off = 1; off < 1024; off <<= 1) {
    int u = (t >= off) ? sm[t - off] : 0;
    __syncthreads();
    sm[t] += u;
    __syncthreads();
  }
  if (t < nb) bsum[t] = sm[t] - v;  // exclusive
}

__global__ __launch_bounds__(SCAN_TPB) void scatter_scan_kernel(
    int* cntcur, const int* __restrict__ bsum,
    int* __restrict__ row_ptr, int n, int total) {
  __shared__ int sm[SCAN_TPB];
  int t = threadIdx.x;
  int lo = blockIdx.x * SCAN_EPB + t * SCAN_EPT;
  int loc[SCAN_EPT];
  int s = 0;
#pragma unroll
  for (int i = 0; i < SCAN_EPT; ++i) {
    int idx = lo + i;
    int c = (idx < n) ? cntcur[idx] : 0;
    loc[i] = s; s += c;
  }
  sm[t] = s;
  __syncthreads();
  for (int off = 1; off < SCAN_TPB; off <<= 1) {
    int u = (t >= off) ? sm[t - off] : 0;
    __syncthreads();
    sm[t] += u;
    __syncthreads();
  }
  int base = sm[t] - s + bsum[blockIdx.x];
#pragma unroll
  for (int i = 0; i < SCAN_EPT; ++i) {
    int idx = lo + i;
    if (idx < n) { int v = base + loc[i]; row_ptr[idx] = v; cntcur[idx] = v; }
  }
  if (blockIdx.x == 0 && t == 0) row_ptr[n] = total;
}

__global__ void fill_kernel(const int* __restrict__ ei, int* __restrict__ cursor,
                            int* __restrict__ col_idx, int E) {
  int e = blockIdx.x * 256 + threadIdx.x;
  if (e < E) {
    int d = ei[E + e];
    int p = atomicAdd(&cursor[d], 1);
    col_idx[p] = ei[e];
  }
}

// ---------------- W prep (sage): fp32 [3][DOUT][128] (Wl,Wr) -> f16 k-tiled ----
__global__ void wprep_kernel(const float* __restrict__ Wl, const float* __restrict__ Wr,
                             ushort_t* __restrict__ dst, int DOUT) {
  int idx = blockIdx.x * 256 + threadIdx.x;
  int per_mat = DOUT * 128;
  int total = 3 * 2 * per_mat;
  if (idx >= total) return;
  int et = idx / (2 * per_mat);
  int r = idx % (2 * per_mat);
  int mat = r / per_mat;
  int e = r % per_mat;
  int nrow = e / 128, k = e % 128;
  const float* src = mat ? Wr : Wl;
  float w = src[et * per_mat + nrow * 128 + k];
  int kt = k >> 5, kk = k & 31;
  int pos = kt * DOUT * 32 + nrow * 32 + kk;
  int MB = 4 * DOUT * 32;
  dst[(size_t)et * (8 * DOUT * 32) + (size_t)mat * MB + pos] = f2h(w);
}

// ---------------- W prep (single matrix [DOUT][K]) -> [kt][DOUT][32] f16 ----
__global__ void wprep_one_kernel(const float* __restrict__ W, ushort_t* __restrict__ dst,
                                 int DOUT, int K) {
  int idx = blockIdx.x * 256 + threadIdx.x;
  if (idx >= DOUT * K) return;
  int row = idx / K, k = idx % K;
  int kt = k >> 5, kk = k & 31;
  dst[kt * DOUT * 32 + row * 32 + kk] = f2h(W[idx]);
}

// ---------------- input projection via MFMA: out[n][128] = X[n][K] @ W.T + b ----
template<int K>
__global__ __launch_bounds__(256, 4) void proj_mfma_kernel(
    const float* __restrict__ X, const ushort_t* __restrict__ WP,
    const float* __restrict__ bias, ushort_t* __restrict__ out, int n) {
  constexpr int KT = K / 32;
  __shared__ __align__(16) ushort_t ah[32][64];
  const int tid = threadIdx.x, lane = tid & 63, wv = tid >> 6;
  const int base = blockIdx.x * 32;

  if (K == 64) {
    for (int r = wv; r < 32; r += 4) {
      int row = base + r;
      float v = (row < n) ? X[(size_t)row * 64 + lane] : 0.f;
      char* rp = (char*)&ah[r][0];
      int swz = (r & 7) << 4;
      *(ushort_t*)(rp + ((2 * lane) ^ swz)) = f2h(v);
    }
  } else {
    for (int r = wv; r < 16; r += 4) {
      int rr = 2 * r + (lane >> 5);
      int row = base + rr;
      int el = lane & 31;
      float v = (row < n) ? X[(size_t)row * K + el] : 0.f;
      char* rp = (char*)&ah[rr][0];
      int swz = (rr & 7) << 4;
      *(ushort_t*)(rp + ((2 * el) ^ swz)) = f2h(v);
    }
  }
  __syncthreads();

  const int rt = wv >> 1, half = wv & 1;
  const int colbase = half * 64;
  const int cn = lane & 15, g = lane >> 4;

  f32x4 acc[4];
#pragma unroll
  for (int ct = 0; ct < 4; ++ct) {
    float b = bias[colbase + ct * 16 + cn];
    acc[ct] = (f32x4){b, b, b, b};
  }

  const int arow = rt * 16 + cn;
  const char* rowp = (const char*)&ah[arow][0];
  const int swz = (arow & 7) << 4;

#pragma unroll
  for (int kt = 0; kt < KT; ++kt) {
    h8 a = *(const h8*)(rowp + ((kt * 64 + g * 16) ^ swz));
#pragma unroll
    for (int ct = 0; ct < 4; ++ct) {
      int wb = kt * 128 * 32 + (colbase + ct * 16 + cn) * 32 + 8 * g;
      h8 wh = *(const h8*)(WP + wb);
      acc[ct] = __builtin_amdgcn_mfma_f32_16x16x32_f16(a, wh, acc[ct], 0, 0, 0);
    }
  }

#pragma unroll
  for (int i = 0; i < 4; ++i) {
    int rloc = rt * 16 + g * 4 + i;
    int row = base + rloc;
    if (row < n) {
      ushort_t* op = out + (size_t)row * 128 + colbase + cn;
#pragma unroll
      for (int ct = 0; ct < 4; ++ct) op[ct * 16] = f2h(acc[ct][i]);
    }
  }
}

// ---- gather helpers (packed-f16 accumulation, interleaved streams) ----
__device__ __forceinline__ void acc4pk(h2* s, uint4 v) {
  h2 a, b, c, d;
  __builtin_memcpy(&a, &v.x, 4);
  __builtin_memcpy(&b, &v.y, 4);
  __builtin_memcpy(&c, &v.z, 4);
  __builtin_memcpy(&d, &v.w, 4);
  s[0] += a; s[1] += b; s[2] += c; s[3] += d;   // v_pk_add_f16
}

__device__ __forceinline__ int sidx(const int* cis, const int* __restrict__ gci,
                                    int b0, int p) {
  return (p < CIS_CAP) ? cis[p] : gci[b0 + p];
}

__device__ __forceinline__ uint4 rowld(const ushort_t* __restrict__ src, int nid, int wq) {
  return ((const uint4*)(src + (size_t)nid * 128))[wq];
}

// mean = packed sums * (1/deg), repacked to 8 f16
__device__ __forceinline__ uint4 pack_mean(const h2* s, float rcf) {
  _Float16 rc = (_Float16)rcf;
  h2 rc2 = {rc, rc};
  h2 r0 = s[0] * rc2, r1 = s[1] * rc2, r2 = s[2] * rc2, r3 = s[3] * rc2;
  uint4 o;
  __builtin_memcpy(&o.x, &r0, 4);
  __builtin_memcpy(&o.y, &r1, 4);
  __builtin_memcpy(&o.z, &r2, 4);
  __builtin_memcpy(&o.w, &r3, 4);
  return o;
}

// ---------------- fused SAGE via MFMA (BM=32), 2-stream interleaved gather ----
template<int DOUT>
__global__ __launch_bounds__(256, 7) void sage_mfma_kernel(
    const int* __restrict__ row_ptr, const int* __restrict__ col_idx,
    const ushort_t* __restrict__ xsrc, const ushort_t* __restrict__ xd,
    const ushort_t* __restrict__ Wb, const float* __restrict__ bl,
    ushort_t* __restrict__ out, int n) {
  constexpr int NCT = DOUT / 32;
  constexpr int MB = 4 * DOUT * 32;
  __shared__ __align__(16) ushort_t am[32][128];
  __shared__ int rps[33];
  __shared__ int cis[CIS_CAP];
  __shared__ float ssb[32][2];
  const int tid = threadIdx.x, lane = tid & 63, wv = tid >> 6;
  const int grp = tid >> 4, wq = tid & 15;
  const int base = blockIdx.x * 32;

  if (tid < 33) rps[tid] = row_ptr[imin(base + tid, n)];
  __syncthreads();
  {
    int bb = rps[0];
    int lim = imin(rps[32] - bb, CIS_CAP);
    for (int i = tid; i < lim; i += 256) cis[i] = col_idx[bb + i];
  }
  __syncthreads();

  // group grp owns rows 2*grp, 2*grp+1; interleave both rows, 2-way unroll each
  {
    const int r0 = grp << 1, r1 = r0 | 1;
    const int bb = rps[0];
    int p0 = rps[r0] - bb, e0 = rps[r0 + 1] - bb;
    int p1 = rps[r1] - bb, e1 = rps[r1 + 1] - bb;
    float rc0 = (e0 > p0) ? 1.f / (float)(e0 - p0) : 0.f;
    float rc1 = (e1 > p1) ? 1.f / (float)(e1 - p1) : 0.f;
    h2 s0[4] = {h2{0, 0}, h2{0, 0}, h2{0, 0}, h2{0, 0}};
    h2 s1[4] = {h2{0, 0}, h2{0, 0}, h2{0, 0}, h2{0, 0}};
    while ((p0 < e0) || (p1 < e1)) {
      bool a0 = p0 < e0, a0b = p0 + 1 < e0;
      bool a1 = p1 < e1, a1b = p1 + 1 < e1;
      uint4 v0a, v0b, v1a, v1b;
      if (a0)  v0a = rowld(xsrc, sidx(cis, col_idx, bb, p0), wq);
      if (a0b) v0b = rowld(xsrc, sidx(cis, col_idx, bb, p0 + 1), wq);
      if (a1)  v1a = rowld(xsrc, sidx(cis, col_idx, bb, p1), wq);
      if (a1b) v1b = rowld(xsrc, sidx(cis, col_idx, bb, p1 + 1), wq);
      if (a0)  { acc4pk(s0, v0a); ++p0; }
      if (a0b) { acc4pk(s0, v0b); ++p0; }
      if (a1)  { acc4pk(s1, v1a); ++p1; }
      if (a1b) { acc4pk(s1, v1b); ++p1; }
    }
    int bo0 = (wq * 16) ^ ((r0 & 7) << 4);
    int bo1 = (wq * 16) ^ ((r1 & 7) << 4);
    *(uint4*)((char*)&am[r0][0] + bo0) = pack_mean(s0, rc0);
    *(uint4*)((char*)&am[r1][0] + bo1) = pack_mean(s1, rc1);
  }
  __syncthreads();

  const int rt = wv >> 1, half = wv & 1;
  const int colbase = half * (DOUT / 2);
  const int cn = lane & 15, g = lane >> 4;

  f32x4 acc[NCT];
#pragma unroll
  for (int ct = 0; ct < NCT; ++ct) {
    float b = bl[colbase + ct * 16 + cn];
    acc[ct] = (f32x4){b, b, b, b};
  }

  const int arow = rt * 16 + cn;
  const char* amrow = (const char*)&am[arow][0];
  const int axor = (arow & 7) << 4;
  const ushort_t* xrow = xd + (size_t)imin(base + arow, n - 1) * 128;

#pragma unroll
  for (int kt = 0; kt < 4; ++kt) {
    int aoff = (kt * 64 + g * 16) ^ axor;
    h8 a_m = *(const h8*)(amrow + aoff);
    h8 a_x = *(const h8*)((const char*)xrow + kt * 64 + g * 16);
    int nbase = kt * DOUT * 32 + (colbase + cn) * 32 + 8 * g;
#pragma unroll
    for (int ct = 0; ct < NCT; ++ct) {
      int no = nbase + ct * 16 * 32;
      h8 wl = *(const h8*)(Wb + 0 * MB + no);
      h8 wr = *(const h8*)(Wb + 1 * MB + no);
      acc[ct] = __builtin_amdgcn_mfma_f32_16x16x32_f16(a_m, wl, acc[ct], 0, 0, 0);
      acc[ct] = __builtin_amdgcn_mfma_f32_16x16x32_f16(a_x, wr, acc[ct], 0, 0, 0);
    }
  }

  float p[4];
#pragma unroll
  for (int i = 0; i < 4; ++i) {
    float s = 0.f;
#pragma unroll
    for (int ct = 0; ct < NCT; ++ct) s += acc[ct][i] * acc[ct][i];
#pragma unroll
    for (int m = 1; m < 16; m <<= 1) s += __shfl_xor(s, m);
    p[i] = s;
  }
  if (cn == 0) {
#pragma unroll
    for (int i = 0; i < 4; ++i) ssb[rt * 16 + g * 4 + i][half] = p[i];
  }
  __syncthreads();

#pragma unroll
  for (int i = 0; i < 4; ++i) {
    int rloc = rt * 16 + g * 4 + i;
    int row = base + rloc;
    float ss = ssb[rloc][0] + ssb[rloc][1];
    float rn = 1.0f / fmaxf(sqrtf(ss), 1e-12f);
    if (row < n) {
      ushort_t* op = out + (size_t)row * DOUT + colbase + cn;
#pragma unroll
      for (int ct = 0; ct < NCT; ++ct) op[ct * 16] = f2h(acc[ct][i] * rn);
    }
  }
}

// ---------------- merged account SAGE (BM=32), 4-stream interleaved gather ----
template<int DOUT>
__global__ __launch_bounds__(256, 6) void sage2_mfma_kernel(
    const int* __restrict__ rp1, const int* __restrict__ ci1, const ushort_t* __restrict__ src1,
    const int* __restrict__ rp2, const int* __restrict__ ci2, const ushort_t* __restrict__ src2,
    const ushort_t* __restrict__ Wb1, const ushort_t* __restrict__ Wb2,
    const float* __restrict__ bl1, const float* __restrict__ bl2,
    ushort_t* __restrict__ out, int n) {
  constexpr int NCT = DOUT / 32;
  constexpr int MB = 4 * DOUT * 32;
  __shared__ __align__(16) ushort_t a1[32][128];
  __shared__ __align__(16) ushort_t a2[32][128];
  __shared__ int rps1[33], rps2[33];
  __shared__ int cis1[CIS_CAP], cis2[CIS_CAP];
  __shared__ float ssb1[32][2], ssb2[32][2];
  const int tid = threadIdx.x, lane = tid & 63, wv = tid >> 6;
  const int grp = tid >> 4, wq = tid & 15;
  const int base = blockIdx.x * 32;

  if (tid < 33) rps1[tid] = rp1[imin(base + tid, n)];
  else if (tid < 66) rps2[tid - 33] = rp2[imin(base + (tid - 33), n)];
  __syncthreads();
  {
    int b1v = rps1[0];
    int lim1 = imin(rps1[32] - b1v, CIS_CAP);
    for (int i = tid; i < lim1; i += 256) cis1[i] = ci1[b1v + i];
    int b2v = rps2[0];
    int lim2 = imin(rps2[32] - b2v, CIS_CAP);
    for (int i = tid; i < lim2; i += 256) cis2[i] = ci2[b2v + i];
  }
  __syncthreads();

  // group grp owns rows 2*grp, 2*grp+1; 4 streams (2 rows x 2 CSRs) x 2-way unroll
  {
    const int r0 = grp << 1, r1 = r0 | 1;
    const int b1v = rps1[0], b2v = rps2[0];
    int pA0 = rps1[r0] - b1v, eA0 = rps1[r0 + 1] - b1v;
    int pA1 = rps1[r1] - b1v, eA1 = rps1[r1 + 1] - b1v;
    int pB0 = rps2[r0] - b2v, eB0 = rps2[r0 + 1] - b2v;
    int pB1 = rps2[r1] - b2v, eB1 = rps2[r1 + 1] - b2v;
    float rcA0 = (eA0 > pA0) ? 1.f / (float)(eA0 - pA0) : 0.f;
    float rcA1 = (eA1 > pA1) ? 1.f / (float)(eA1 - pA1) : 0.f;
    float rcB0 = (eB0 > pB0) ? 1.f / (float)(eB0 - pB0) : 0.f;
    float rcB1 = (eB1 > pB1) ? 1.f / (float)(eB1 - pB1) : 0.f;
    h2 sA0[4] = {h2{0, 0}, h2{0, 0}, h2{0, 0}, h2{0, 0}};
    h2 sA1[4] = {h2{0, 0}, h2{0, 0}, h2{0, 0}, h2{0, 0}};
    h2 sB0[4] = {h2{0, 0}, h2{0, 0}, h2{0, 0}, h2{0, 0}};
    h2 sB1[4] = {h2{0, 0}, h2{0, 0}, h2{0, 0}, h2{0, 0}};
    while ((pA0 < eA0) || (pA1 < eA1) || (pB0 < eB0) || (pB1 < eB1)) {
      bool aA0 = pA0 < eA0, bA0 = pA0 + 1 < eA0;
      bool aA1 = pA1 < eA1, bA1 = pA1 + 1 < eA1;
      bool aB0 = pB0 < eB0, bB0 = pB0 + 1 < eB0;
      bool aB1 = pB1 < eB1, bB1 = pB1 + 1 < eB1;
      uint4 vA0a, vA0b, vA1a, vA1b, vB0a, vB0b, vB1a, vB1b;
      if (aA0) vA0a = rowld(src1, sidx(cis1, ci1, b1v, pA0), wq);
      if (bA0) vA0b = rowld(src1, sidx(cis1, ci1, b1v, pA0 + 1), wq);
      if (aA1) vA1a = rowld(src1, sidx(cis1, ci1, b1v, pA1), wq);
      if (bA1) vA1b = rowld(src1, sidx(cis1, ci1, b1v, pA1 + 1), wq);
      if (aB0) vB0a = rowld(src2, sidx(cis2, ci2, b2v, pB0), wq);
      if (bB0) vB0b = rowld(src2, sidx(cis2, ci2, b2v, pB0 + 1), wq);
      if (aB1) vB1a = rowld(src2, sidx(cis2, ci2, b2v, pB1), wq);
      if (bB1) vB1b = rowld(src2, sidx(cis2, ci2, b2v, pB1 + 1), wq);
      if (aA0) { acc4pk(sA0, vA0a); ++pA0; }
      if (bA0) { acc4pk(sA0, vA0b); ++pA0; }
      if (aA1) { acc4pk(sA1, vA1a); ++pA1; }
      if (bA1) { acc4pk(sA1, vA1b); ++pA1; }
      if (aB0) { acc4pk(sB0, vB0a); ++pB0; }
      if (bB0) { acc4pk(sB0, vB0b); ++pB0; }
      if (aB1) { acc4pk(sB1, vB1a); ++pB1; }
      if (bB1) { acc4pk(sB1, vB1b); ++pB1; }
    }
    int bo0 = (wq * 16) ^ ((r0 & 7) << 4);
    int bo1 = (wq * 16) ^ ((r1 & 7) << 4);
    *(uint4*)((char*)&a1[r0][0] + bo0) = pack_mean(sA0, rcA0);
    *(uint4*)((char*)&a1[r1][0] + bo1) = pack_mean(sA1, rcA1);
    *(uint4*)((char*)&a2[r0][0] + bo0) = pack_mean(sB0, rcB0);
    *(uint4*)((char*)&a2[r1][0] + bo1) = pack_mean(sB1, rcB1);
  }
  __syncthreads();

  const int rt = wv >> 1, half = wv & 1;
  const int colbase = half * (DOUT / 2);
  const int cn = lane & 15, g = lane >> 4;

  f32x4 acc1[NCT], acc2[NCT];
#pragma unroll
  for (int ct = 0; ct < NCT; ++ct) {
    float b1b = bl1[colbase + ct * 16 + cn];
    float b2b = bl2[colbase + ct * 16 + cn];
    acc1[ct] = (f32x4){b1b, b1b, b1b, b1b};
    acc2[ct] = (f32x4){b2b, b2b, b2b, b2b};
  }

  const int arow = rt * 16 + cn;
  const char* r1p = (const char*)&a1[arow][0];
  const char* r2p = (const char*)&a2[arow][0];
  const int axor = (arow & 7) << 4;
  const ushort_t* xrow = src2 + (size_t)imin(base + arow, n - 1) * 128;

#pragma unroll
  for (int kt = 0; kt < 4; ++kt) {
    int aoff = (kt * 64 + g * 16) ^ axor;
    h8 f1 = *(const h8*)(r1p + aoff);
    h8 f2 = *(const h8*)(r2p + aoff);
    h8 fx = *(const h8*)((const char*)xrow + kt * 64 + g * 16);
    int nbase = kt * DOUT * 32 + (colbase + cn) * 32 + 8 * g;
#pragma unroll
    for (int ct = 0; ct < NCT; ++ct) {
      int no = nbase + ct * 16 * 32;
      h8 wl1 = *(const h8*)(Wb1 + 0 * MB + no);
      h8 wr1 = *(const h8*)(Wb1 + 1 * MB + no);
      h8 wl2 = *(const h8*)(Wb2 + 0 * MB + no);
      h8 wr2 = *(const h8*)(Wb2 + 1 * MB + no);
      acc1[ct] = __builtin_amdgcn_mfma_f32_16x16x32_f16(f1, wl1, acc1[ct], 0, 0, 0);
      acc1[ct] = __builtin_amdgcn_mfma_f32_16x16x32_f16(fx, wr1, acc1[ct], 0, 0, 0);
      acc2[ct] = __builtin_amdgcn_mfma_f32_16x16x32_f16(f2, wl2, acc2[ct], 0, 0, 0);
      acc2[ct] = __builtin_amdgcn_mfma_f32_16x16x32_f16(fx, wr2, acc2[ct], 0, 0, 0);
    }
  }

#pragma unroll
  for (int i = 0; i < 4; ++i) {
    float s1 = 0.f, s2 = 0.f;
#pragma unroll
    for (int ct = 0; ct < NCT; ++ct) {
      s1 += acc1[ct][i] * acc1[ct][i];
      s2 += acc2[ct][i] * acc2[ct][i];
    }
#pragma unroll
    for (int m = 1; m < 16; m <<= 1) {
      s1 += __shfl_xor(s1, m);
      s2 += __shfl_xor(s2, m);
    }
    if (cn == 0) {
      ssb1[rt * 16 + g * 4 + i][half] = s1;
      ssb2[rt * 16 + g * 4 + i][half] = s2;
    }
  }
  __syncthreads();

#pragma unroll
  for (int i = 0; i < 4; ++i) {
    int rloc = rt * 16 + g * 4 + i;
    int row = base + rloc;
    float rn1 = 1.0f / fmaxf(sqrtf(ssb1[rloc][0] + ssb1[rloc][1]), 1e-12f);
    float rn2 = 1.0f / fmaxf(sqrtf(ssb2[rloc][0] + ssb2[rloc][1]), 1e-12f);
    if (row < n) {
      ushort_t* op = out + (size_t)row * DOUT + colbase + cn;
#pragma unroll
      for (int ct = 0; ct < NCT; ++ct)
        op[ct * 16] = f2h(acc1[ct][i] * rn1 + acc2[ct][i] * rn2);
    }
  }
}

// ---------------- BN stats, vectorized ----------------
template<int C>
__global__ __launch_bounds__(256) void bn_stats_kernel(const ushort_t* __restrict__ x,
    float* __restrict__ stats, int n) {
  constexpr int TPR = C / 8;
  constexpr int RPB = 256 / TPR;
  __shared__ float smw[4][TPR][16];
  const int tid = threadIdx.x, lane = tid & 63, wv = tid >> 6;
  const int cg = tid % TPR;
  const int r0 = tid / TPR;

  float s[8] = {0.f, 0.f, 0.f, 0.f, 0.f, 0.f, 0.f, 0.f};
  float q[8] = {0.f, 0.f, 0.f, 0.f, 0.f, 0.f, 0.f, 0.f};
  for (int r = blockIdx.x * RPB + r0; r < n; r += gridDim.x * RPB) {
    uint4 v = ((const uint4*)(x + (size_t)r * C))[cg];
    unsigned w[4] = {v.x, v.y, v.z, v.w};
#pragma unroll
    for (int j = 0; j < 4; ++j) {
      float a = hlo(w[j]), b = hhi(w[j]);
      s[2 * j] += a; q[2 * j] += a * a;
      s[2 * j + 1] += b; q[2 * j + 1] += b * b;
    }
  }
#pragma unroll
  for (int j = 0; j < 8; ++j) {
    for (int m = TPR; m < 64; m <<= 1) {
      s[j] += __shfl_xor(s[j], m);
      q[j] += __shfl_xor(q[j], m);
    }
  }
  if (lane < TPR) {
#pragma unroll
    for (int j = 0; j < 8; ++j) {
      smw[wv][lane][j] = s[j];
      smw[wv][lane][8 + j] = q[j];
    }
  }
  __syncthreads();
  if (tid < C) {
    int g2 = tid >> 3, j = tid & 7;
    float ts = smw[0][g2][j] + smw[1][g2][j] + smw[2][g2][j] + smw[3][g2][j];
    float tq = smw[0][g2][8 + j] + smw[1][g2][8 + j] + smw[2][g2][8 + j] + smw[3][g2][8 + j];
    atomicAdd(&stats[tid], ts);
    atomicAdd(&stats[C + tid], tq);
  }
}

// ---------------- BN apply (+ReLU), vectorized 8 f16/thread ----------------
template<int C, bool RELU>
__global__ __launch_bounds__(256) void bn_apply_kernel(ushort_t* __restrict__ x,
    const float* __restrict__ stats, const float* __restrict__ g,
    const float* __restrict__ b, int n) {
  size_t i = (size_t)blockIdx.x * 256 + threadIdx.x;
  size_t total = (size_t)n * C / 8;
  if (i >= total) return;
  int c0 = (int)((i * 8) & (C - 1));
  float rn = 1.f / (float)n;
  uint4 v = ((const uint4*)x)[i];
  unsigned w[4] = {v.x, v.y, v.z, v.w};
  unsigned o[4];
#pragma unroll
  for (int j = 0; j < 4; ++j) {
    int cA = c0 + 2 * j, cB = cA + 1;
    float muA = stats[cA] * rn, muB = stats[cB] * rn;
    float vaA = stats[C + cA] * rn - muA * muA;
    float vaB = stats[C + cB] * rn - muB * muB;
    float xA = (hlo(w[j]) - muA) * rsqrtf(vaA + EPS_BN) * g[cA] + b[cA];
    float xB = (hhi(w[j]) - muB) * rsqrtf(vaB + EPS_BN) * g[cB] + b[cB];
    if (RELU) { xA = fmaxf(xA, 0.f); xB = fmaxf(xB, 0.f); }
    o[j] = (unsigned)f2h(xA) | ((unsigned)f2h(xB) << 16);
  }
  ((uint4*)x)[i] = make_uint4(o[0], o[1], o[2], o[3]);
}

// ---------------- classifier via MFMA: out[n] = relu(X@W1.T+b1) @ W2.T + b2 ---
__global__ __launch_bounds__(256, 4) void clf_mfma_kernel(
    const ushort_t* __restrict__ X, const ushort_t* __restrict__ WPc,
    const float* __restrict__ b1, const float* __restrict__ W2,
    const float* __restrict__ b2, float* __restrict__ out, int n) {
  __shared__ __align__(16) ushort_t axl[32][64];
  __shared__ float ssb[32][2];
  const int tid = threadIdx.x, lane = tid & 63, wv = tid >> 6;
  const int base = blockIdx.x * 32;

  for (int r = wv; r < 16; r += 4) {
    int rr = 2 * r + (lane >> 5);
    int row = base + rr;
    int el = lane & 31;
    unsigned v = (row < n) ? ((const unsigned*)(X + (size_t)row * 64))[el] : 0u;
    int swz = (rr & 7) << 4;
    *(unsigned*)((char*)&axl[rr][0] + ((4 * el) ^ swz)) = v;
  }
  __syncthreads();

  const int rt = wv >> 1, half = wv & 1;
  const int colbase = half * 32;
  const int cn = lane & 15, g = lane >> 4;

  f32x4 acc[2];
#pragma unroll
  for (int ct = 0; ct < 2; ++ct) {
    float b = b1[colbase + ct * 16 + cn];
    acc[ct] = (f32x4){b, b, b, b};
  }

  const int arow = rt * 16 + cn;
  const char* rowp = (const char*)&axl[arow][0];
  const int swz = (arow & 7) << 4;

#pragma unroll
  for (int kt = 0; kt < 2; ++kt) {
    h8 a = *(const h8*)(rowp + ((kt * 64 + g * 16) ^ swz));
#pragma unroll
    for (int ct = 0; ct < 2; ++ct) {
      int wb = kt * 64 * 32 + (colbase + ct * 16 + cn) * 32 + 8 * g;
      h8 wh = *(const h8*)(WPc + wb);
      acc[ct] = __builtin_amdgcn_mfma_f32_16x16x32_f16(a, wh, acc[ct], 0, 0, 0);
    }
  }

  float w2v0 = W2[colbase + cn], w2v1 = W2[colbase + 16 + cn];
#pragma unroll
  for (int i = 0; i < 4; ++i) {
    float p = fmaxf(acc[0][i], 0.f) * w2v0 + fmaxf(acc[1][i], 0.f) * w2v1;
#pragma unroll
    for (int m = 1; m < 16; m <<= 1) p += __shfl_xor(p, m);
    if (cn == 0) ssb[rt * 16 + g * 4 + i][half] = p;
  }
  __syncthreads();

  if (tid < 32) {
    int row = base + tid;
    if (row < n) out[row] = ssb[tid][0] + ssb[tid][1] + b2[0];
  }
}

// ---------------- one hetero layer ----------------
template<int DO, bool RELU>
static void run_layer(const ushort_t* WB, const float* bl,
                      const float* g, const float* b,
                      const ushort_t* xa, const ushort_t* xm,
                      ushort_t* oa, ushort_t* om, float* STATS,
                      const int* rp_p, const int* ci_p,
                      const int* rp_r, const int* ci_r,
                      const int* rp_t, const int* ci_t,
                      int NA, int NM, hipStream_t stream) {
  const size_t ETS = (size_t)8 * DO * 32;
  float* stA = STATS;
  float* stM = STATS + 2 * DO;
  hipMemsetAsync(STATS, 0, 4 * DO * sizeof(float), stream);
  sage_mfma_kernel<DO><<<idiv(NM, 32), 256, 0, stream>>>(
      rp_p, ci_p, xa, xm, WB + 0 * ETS, bl, om, NM);
  sage2_mfma_kernel<DO><<<idiv(NA, 32), 256, 0, stream>>>(
      rp_r, ci_r, xm, rp_t, ci_t, xa,
      WB + 1 * ETS, WB + 2 * ETS, bl + DO, bl + 2 * DO, oa, NA);
  bn_stats_kernel<DO><<<256, 256, 0, stream>>>(oa, stA, NA);
  bn_stats_kernel<DO><<<256, 256, 0, stream>>>(om, stM, NM);
  bn_apply_kernel<DO, RELU><<<idiv(NA * DO / 8, 256), 256, 0, stream>>>(oa, stA, g, b, NA);
  bn_apply_kernel<DO, RELU><<<idiv(NM * DO / 8, 256), 256, 0, stream>>>(om, stM, g + DO, b + DO, NM);
}

static size_t ws_need(int NA, int NM, int E) {
  size_t acts = ((size_t)2 * NA * 128 + (size_t)2 * NM * 128) * 2;
  size_t wbuf = ((size_t)2 * 98304 + 49152 + 8192 + 4096 + 4096) * 2;
  size_t stats = 1024 * 4;
  size_t ints = ((size_t)(NM + 1) + NM + E
               + 2 * ((size_t)(NA + 1) + NA + E) + 1024) * 4;
  return acts + wbuf + stats + ints + 256;
}

extern "C" void kernel_launch(void* const* d_in, const int* in_sizes, int n_in,
                              void* d_out, int out_size, void* d_ws, size_t ws_size,
                              hipStream_t stream) {
  const int NA = in_sizes[0] / 64;   // 200000
  const int NM = in_sizes[1] / 32;   // 100000
  const int E  = in_sizes[2] / 2;    // 500000
  if (ws_size < ws_need(NA, NM, E)) return;

  const float* x_acc = (const float*)d_in[0];
  const float* x_mer = (const float*)d_in[1];
  const int* ei_pays = (const int*)d_in[2];
  const int* ei_rev  = (const int*)d_in[3];
  const int* ei_tr   = (const int*)d_in[4];
  const float* pWa = (const float*)d_in[5];
  const float* pba = (const float*)d_in[6];
  const float* pWm = (const float*)d_in[7];
  const float* pbm = (const float*)d_in[8];
  const float* Wl[3]  = {(const float*)d_in[9],  (const float*)d_in[12], (const float*)d_in[15]};
  const float* blp[3] = {(const float*)d_in[10], (const float*)d_in[13], (const float*)d_in[16]};
  const float* Wr[3]  = {(const float*)d_in[11], (const float*)d_in[14], (const float*)d_in[17]};
  const float* bng[3] = {(const float*)d_in[18], (const float*)d_in[20], (const float*)d_in[22]};
  const float* bnb[3] = {(const float*)d_in[19], (const float*)d_in[21], (const float*)d_in[23]};
  const float* cW1 = (const float*)d_in[24];
  const float* cb1 = (const float*)d_in[25];
  const float* cW2 = (const float*)d_in[26];
  const float* cb2 = (const float*)d_in[27];

  char* p = (char*)d_ws;
  ushort_t* A0 = (ushort_t*)p; p += (size_t)NA * 128 * 2;
  ushort_t* A1 = (ushort_t*)p; p += (size_t)NA * 128 * 2;
  ushort_t* M0 = (ushort_t*)p; p += (size_t)NM * 128 * 2;
  ushort_t* M1 = (ushort_t*)p; p += (size_t)NM * 128 * 2;
  ushort_t* WB0 = (ushort_t*)p; p += (size_t)98304 * 2;
  ushort_t* WB1 = (ushort_t*)p; p += (size_t)98304 * 2;
  ushort_t* WB2 = (ushort_t*)p; p += (size_t)49152 * 2;
  ushort_t* WPA = (ushort_t*)p; p += (size_t)8192 * 2;
  ushort_t* WPM = (ushort_t*)p; p += (size_t)4096 * 2;
  ushort_t* WPC = (ushort_t*)p; p += (size_t)4096 * 2;
  p = (char*)(((uintptr_t)p + 15) & ~(uintptr_t)15);
  float* STATS = (float*)p; p += 1024 * 4;
  int* rp_p  = (int*)p; p += ((size_t)NM + 1) * 4;
  int* cur_p = (int*)p; p += (size_t)NM * 4;
  int* ci_p  = (int*)p; p += (size_t)E * 4;
  int* rp_r  = (int*)p; p += ((size_t)NA + 1) * 4;
  int* cur_r = (int*)p; p += (size_t)NA * 4;
  int* ci_r  = (int*)p; p += (size_t)E * 4;
  int* rp_t  = (int*)p; p += ((size_t)NA + 1) * 4;
  int* cur_t = (int*)p; p += (size_t)NA * 4;
  int* ci_t  = (int*)p; p += (size_t)E * 4;
  int* bsum  = (int*)p; p += 1024 * 4;

  struct ET { const int* ei; int nd; int* rp; int* cur; int* ci; };
  ET et[3] = {
      {ei_pays, NM, rp_p, cur_p, ci_p},
      {ei_rev,  NA, rp_r, cur_r, ci_r},
      {ei_tr,   NA, rp_t, cur_t, ci_t},
  };
  for (int t = 0; t < 3; ++t) {
    hipMemsetAsync(et[t].cur, 0, (size_t)et[t].nd * sizeof(int), stream);
    cnt_kernel<<<idiv(E, 256), 256, 0, stream>>>(et[t].ei, et[t].cur, E);
    int nb = idiv(et[t].nd, SCAN_EPB);
    bsum_kernel<<<nb, SCAN_TPB, 0, stream>>>(et[t].cur, bsum, et[t].nd);
    bscan_kernel<<<1, 1024, 0, stream>>>(bsum, nb);
    scatter_scan_kernel<<<nb, SCAN_TPB, 0, stream>>>(et[t].cur, bsum, et[t].rp,
                                                     et[t].nd, E);
    fill_kernel<<<idiv(E, 256), 256, 0, stream>>>(et[t].ei, et[t].cur, et[t].ci, E);
  }

  wprep_kernel<<<idiv(3 * 2 * 128 * 128, 256), 256, 0, stream>>>(Wl[0], Wr[0], WB0, 128);
  wprep_kernel<<<idiv(3 * 2 * 128 * 128, 256), 256, 0, stream>>>(Wl[1], Wr[1], WB1, 128);
  wprep_kernel<<<idiv(3 * 2 * 64 * 128, 256), 256, 0, stream>>>(Wl[2], Wr[2], WB2, 64);
  wprep_one_kernel<<<idiv(128 * 64, 256), 256, 0, stream>>>(pWa, WPA, 128, 64);
  wprep_one_kernel<<<idiv(128 * 32, 256), 256, 0, stream>>>(pWm, WPM, 128, 32);
  wprep_one_kernel<<<idiv(64 * 64, 256), 256, 0, stream>>>(cW1, WPC, 64, 64);

  proj_mfma_kernel<64><<<idiv(NA, 32), 256, 0, stream>>>(x_acc, WPA, pba, A0, NA);
  proj_mfma_kernel<32><<<idiv(NM, 32), 256, 0, stream>>>(x_mer, WPM, pbm, M0, NM);

  ushort_t *xa = A0, *xm = M0, *oa = A1, *om = M1;
  run_layer<128, true>(WB0, blp[0], bng[0], bnb[0], xa, xm, oa, om, STATS,
                       rp_p, ci_p, rp_r, ci_r, rp_t, ci_t, NA, NM, stream);
  { ushort_t* t = xa; xa = oa; oa = t; t = xm; xm = om; om = t; }
  run_layer<128, true>(WB1, blp[1], bng[1], bnb[1], xa, xm, oa, om, STATS,
                       rp_p, ci_p, rp_r, ci_r, rp_t, ci_t, NA, NM, stream);
  { ushort_t* t = xa; xa = oa; oa = t; t = xm; xm = om; om = t; }
  run_layer<64, false>(WB2, blp[2], bng[2], bnb[2], xa, xm, oa, om, STATS,
                       rp_p, ci_p, rp_r, ci_r, rp_t, ci_t, NA, NM, stream);
  { ushort_t* t = xa; xa = oa; oa = t; t = xm; xm = om; om = t; }

  clf_mfma_kernel<<<idiv(NA, 32), 256, 0, stream>>>(xa, WPC, cb1, cW2, cb2,
                                                    (float*)d_out, NA);
}

// Round 16
// 875.454 us; speedup vs baseline: 1.1444x; 1.1444x over previous
//
#include <hip/hip_runtime.h>
#include <cstdint>
#include <cstddef>

#define EPS_BN 1e-5f
#define CIS_CAP 640

typedef unsigned short ushort_t;
typedef _Float16 h8 __attribute__((ext_vector_type(8)));
typedef __attribute__((ext_vector_type(4))) float f32x4;

static inline int idiv(int a, int b) { return (a + b - 1) / b; }

__device__ __forceinline__ float h2f(ushort_t b) {
  _Float16 h; __builtin_memcpy(&h, &b, 2); return (float)h;
}
__device__ __forceinline__ ushort_t f2h(float x) {
  _Float16 h = (_Float16)x; ushort_t b; __builtin_memcpy(&b, &h, 2); return b;
}
__device__ __forceinline__ float hlo(unsigned u) { return h2f((ushort_t)(u & 0xffffu)); }
__device__ __forceinline__ float hhi(unsigned u) { return h2f((ushort_t)(u >> 16)); }
__device__ __forceinline__ int imin(int a, int b) { return a < b ? a : b; }

// ---------------- CSR build (batched over 3 edge types) ----------------
__global__ void cnt3_kernel(const int* __restrict__ ei0, int* __restrict__ c0,
                            const int* __restrict__ ei1, int* __restrict__ c1,
                            const int* __restrict__ ei2, int* __restrict__ c2,
                            int E, int nbPer) {
  int type = blockIdx.x / nbPer;
  int e = (blockIdx.x % nbPer) * 256 + threadIdx.x;
  if (e >= E) return;
  const int* ei = (type == 0) ? ei0 : ((type == 1) ? ei1 : ei2);
  int* c = (type == 0) ? c0 : ((type == 1) ? c1 : c2);
  atomicAdd(&c[ei[E + e]], 1);
}

#define SCAN_TPB 256
#define SCAN_EPT 16
#define SCAN_EPB (SCAN_TPB * SCAN_EPT)

__global__ __launch_bounds__(SCAN_TPB) void bsum3_kernel(
    const int* __restrict__ c0, int n0, const int* __restrict__ c1, int n1,
    const int* __restrict__ c2, int n2, int* __restrict__ bsum,
    int nb0, int nb1) {
  __shared__ int sm[SCAN_TPB];
  int bid = blockIdx.x;
  const int* cnt; int n; int* bs; int lb;
  if (bid < nb0) { cnt = c0; n = n0; bs = bsum; lb = bid; }
  else if (bid < nb0 + nb1) { cnt = c1; n = n1; bs = bsum + 128; lb = bid - nb0; }
  else { cnt = c2; n = n2; bs = bsum + 256; lb = bid - nb0 - nb1; }
  int lo = lb * SCAN_EPB + threadIdx.x * SCAN_EPT;
  int s = 0;
#pragma unroll
  for (int i = 0; i < SCAN_EPT; ++i) { int idx = lo + i; if (idx < n) s += cnt[idx]; }
  sm[threadIdx.x] = s;
  __syncthreads();
  for (int off = SCAN_TPB / 2; off; off >>= 1) {
    if (threadIdx.x < off) sm[threadIdx.x] += sm[threadIdx.x + off];
    __syncthreads();
  }
  if (threadIdx.x == 0) bs[lb] = sm[0];
}

__global__ __launch_bounds__(128) void bscan3_kernel(int* __restrict__ bsum,
                                                     int nb0, int nb1, int nb2) {
  __shared__ int sm[128];
  int* bs = bsum + blockIdx.x * 128;
  int nb = (blockIdx.x == 0) ? nb0 : ((blockIdx.x == 1) ? nb1 : nb2);
  int t = threadIdx.x;
  int v = (t < nb) ? bs[t] : 0;
  sm[t] = v;
  __syncthreads();
  for (int off = 1; off < 128; off <<= 1) {
    int u = (t >= off) ? sm[t - off] : 0;
    __syncthreads();
    sm[t] += u;
    __syncthreads();
  }
  if (t < nb) bs[t] = sm[t] - v;  // exclusive
}

__global__ __launch_bounds__(SCAN_TPB) void scatter3_kernel(
    int* __restrict__ cc0, int* __restrict__ rp0, int n0,
    int* __restrict__ cc1, int* __restrict__ rp1, int n1,
    int* __restrict__ cc2, int* __restrict__ rp2, int n2,
    const int* __restrict__ bsum, int nb0, int nb1, int total) {
  __shared__ int sm[SCAN_TPB];
  int bid = blockIdx.x;
  int* cntcur; int* row_ptr; int n; const int* bs; int lb;
  if (bid < nb0) { cntcur = cc0; row_ptr = rp0; n = n0; bs = bsum; lb = bid; }
  else if (bid < nb0 + nb1) { cntcur = cc1; row_ptr = rp1; n = n1; bs = bsum + 128; lb = bid - nb0; }
  else { cntcur = cc2; row_ptr = rp2; n = n2; bs = bsum + 256; lb = bid - nb0 - nb1; }
  int t = threadIdx.x;
  int lo = lb * SCAN_EPB + t * SCAN_EPT;
  int loc[SCAN_EPT];
  int s = 0;
#pragma unroll
  for (int i = 0; i < SCAN_EPT; ++i) {
    int idx = lo + i;
    int c = (idx < n) ? cntcur[idx] : 0;
    loc[i] = s; s += c;
  }
  sm[t] = s;
  __syncthreads();
  for (int off = 1; off < SCAN_TPB; off <<= 1) {
    int u = (t >= off) ? sm[t - off] : 0;
    __syncthreads();
    sm[t] += u;
    __syncthreads();
  }
  int base = sm[t] - s + bs[lb];
#pragma unroll
  for (int i = 0; i < SCAN_EPT; ++i) {
    int idx = lo + i;
    if (idx < n) { int v = base + loc[i]; row_ptr[idx] = v; cntcur[idx] = v; }
  }
  if (lb == 0 && t == 0) row_ptr[n] = total;
}

__global__ void fill3_kernel(const int* __restrict__ ei0, int* __restrict__ cu0, int* __restrict__ co0,
                             const int* __restrict__ ei1, int* __restrict__ cu1, int* __restrict__ co1,
                             const int* __restrict__ ei2, int* __restrict__ cu2, int* __restrict__ co2,
                             int E, int nbPer) {
  int type = blockIdx.x / nbPer;
  int e = (blockIdx.x % nbPer) * 256 + threadIdx.x;
  if (e >= E) return;
  const int* ei = (type == 0) ? ei0 : ((type == 1) ? ei1 : ei2);
  int* cur = (type == 0) ? cu0 : ((type == 1) ? cu1 : cu2);
  int* ci = (type == 0) ? co0 : ((type == 1) ? co1 : co2);
  int d = ei[E + e];
  int p = atomicAdd(&cur[d], 1);
  ci[p] = ei[e];
}

// ---------------- W prep (sage): fp32 [3][DOUT][128] (Wl,Wr) -> f16 k-tiled ----
__global__ void wprep_kernel(const float* __restrict__ Wl, const float* __restrict__ Wr,
                             ushort_t* __restrict__ dst, int DOUT) {
  int idx = blockIdx.x * 256 + threadIdx.x;
  int per_mat = DOUT * 128;
  int total = 3 * 2 * per_mat;
  if (idx >= total) return;
  int et = idx / (2 * per_mat);
  int r = idx % (2 * per_mat);
  int mat = r / per_mat;
  int e = r % per_mat;
  int nrow = e / 128, k = e % 128;
  const float* src = mat ? Wr : Wl;
  float w = src[et * per_mat + nrow * 128 + k];
  int kt = k >> 5, kk = k & 31;
  int pos = kt * DOUT * 32 + nrow * 32 + kk;
  int MB = 4 * DOUT * 32;
  dst[(size_t)et * (8 * DOUT * 32) + (size_t)mat * MB + pos] = f2h(w);
}

__global__ void wprep_one_kernel(const float* __restrict__ W, ushort_t* __restrict__ dst,
                                 int DOUT, int K) {
  int idx = blockIdx.x * 256 + threadIdx.x;
  if (idx >= DOUT * K) return;
  int row = idx / K, k = idx % K;
  int kt = k >> 5, kk = k & 31;
  dst[kt * DOUT * 32 + row * 32 + kk] = f2h(W[idx]);
}

// ---------------- input projection via MFMA ----------------
template<int K>
__global__ __launch_bounds__(256, 4) void proj_mfma_kernel(
    const float* __restrict__ X, const ushort_t* __restrict__ WP,
    const float* __restrict__ bias, ushort_t* __restrict__ out, int n) {
  constexpr int KT = K / 32;
  __shared__ __align__(16) ushort_t ah[32][64];
  const int tid = threadIdx.x, lane = tid & 63, wv = tid >> 6;
  const int base = blockIdx.x * 32;

  if (K == 64) {
    for (int r = wv; r < 32; r += 4) {
      int row = base + r;
      float v = (row < n) ? X[(size_t)row * 64 + lane] : 0.f;
      char* rp = (char*)&ah[r][0];
      int swz = (r & 7) << 4;
      *(ushort_t*)(rp + ((2 * lane) ^ swz)) = f2h(v);
    }
  } else {
    for (int r = wv; r < 16; r += 4) {
      int rr = 2 * r + (lane >> 5);
      int row = base + rr;
      int el = lane & 31;
      float v = (row < n) ? X[(size_t)row * K + el] : 0.f;
      char* rp = (char*)&ah[rr][0];
      int swz = (rr & 7) << 4;
      *(ushort_t*)(rp + ((2 * el) ^ swz)) = f2h(v);
    }
  }
  __syncthreads();

  const int rt = wv >> 1, half = wv & 1;
  const int colbase = half * 64;
  const int cn = lane & 15, g = lane >> 4;

  f32x4 acc[4];
#pragma unroll
  for (int ct = 0; ct < 4; ++ct) {
    float b = bias[colbase + ct * 16 + cn];
    acc[ct] = (f32x4){b, b, b, b};
  }

  const int arow = rt * 16 + cn;
  const char* rowp = (const char*)&ah[arow][0];
  const int swz = (arow & 7) << 4;

#pragma unroll
  for (int kt = 0; kt < KT; ++kt) {
    h8 a = *(const h8*)(rowp + ((kt * 64 + g * 16) ^ swz));
#pragma unroll
    for (int ct = 0; ct < 4; ++ct) {
      int wb = kt * 128 * 32 + (colbase + ct * 16 + cn) * 32 + 8 * g;
      h8 wh = *(const h8*)(WP + wb);
      acc[ct] = __builtin_amdgcn_mfma_f32_16x16x32_f16(a, wh, acc[ct], 0, 0, 0);
    }
  }

#pragma unroll
  for (int i = 0; i < 4; ++i) {
    int rloc = rt * 16 + g * 4 + i;
    int row = base + rloc;
    if (row < n) {
      ushort_t* op = out + (size_t)row * 128 + colbase + cn;
#pragma unroll
      for (int ct = 0; ct < 4; ++ct) op[ct * 16] = f2h(acc[ct][i]);
    }
  }
}

// ---- group-per-row gather helpers (round-13 proven form) ----
__device__ __forceinline__ void acc8(float* s, uint4 v) {
  s[0] += hlo(v.x); s[1] += hhi(v.x);
  s[2] += hlo(v.y); s[3] += hhi(v.y);
  s[4] += hlo(v.z); s[5] += hhi(v.z);
  s[6] += hlo(v.w); s[7] += hhi(v.w);
}

__device__ __forceinline__ void grp_gather(const int* rps, const int* cis,
                                           const int* __restrict__ gci,
                                           const ushort_t* __restrict__ src,
                                           int rr, int wq, float* s) {
  int b0 = rps[0];
  int p = rps[rr] - b0, e = rps[rr + 1] - b0;
  for (; p + 2 <= e; p += 2) {
    int n0 = (p < CIS_CAP) ? cis[p] : gci[b0 + p];
    int n1 = (p + 1 < CIS_CAP) ? cis[p + 1] : gci[b0 + p + 1];
    uint4 v0 = ((const uint4*)(src + (size_t)n0 * 128))[wq];
    uint4 v1 = ((const uint4*)(src + (size_t)n1 * 128))[wq];
    acc8(s, v0);
    acc8(s, v1);
  }
  if (p < e) {
    int n0 = (p < CIS_CAP) ? cis[p] : gci[b0 + p];
    uint4 v0 = ((const uint4*)(src + (size_t)n0 * 128))[wq];
    acc8(s, v0);
  }
}

__device__ __forceinline__ uint4 pack_h8v(const float* s, float rc) {
  uint4 o;
  o.x = (unsigned)f2h(s[0] * rc) | ((unsigned)f2h(s[1] * rc) << 16);
  o.y = (unsigned)f2h(s[2] * rc) | ((unsigned)f2h(s[3] * rc) << 16);
  o.z = (unsigned)f2h(s[4] * rc) | ((unsigned)f2h(s[5] * rc) << 16);
  o.w = (unsigned)f2h(s[6] * rc) | ((unsigned)f2h(s[7] * rc) << 16);
  return o;
}

// ---------------- combined per-layer SAGE: merchant blocks + account blocks ---
template<int DOUT>
__global__ __launch_bounds__(256, 7) void sage_layer_kernel(
    int nbM,
    const int* __restrict__ rp_p, const int* __restrict__ ci_p,
    const ushort_t* __restrict__ xa, const ushort_t* __restrict__ xm,
    const ushort_t* __restrict__ WbP, const float* __restrict__ blP,
    ushort_t* __restrict__ om, int NM,
    const int* __restrict__ rp_r, const int* __restrict__ ci_r,
    const int* __restrict__ rp_t, const int* __restrict__ ci_t,
    const ushort_t* __restrict__ Wb1, const ushort_t* __restrict__ Wb2,
    const float* __restrict__ bl1, const float* __restrict__ bl2,
    ushort_t* __restrict__ oa, int NA) {
  constexpr int NCT = DOUT / 32;
  constexpr int MB = 4 * DOUT * 32;
  __shared__ __align__(16) ushort_t a1[32][128];
  __shared__ __align__(16) ushort_t a2[32][128];
  __shared__ int rps1[33], rps2[33];
  __shared__ int cis1[CIS_CAP], cis2[CIS_CAP];
  __shared__ float ssb1[32][2], ssb2[32][2];
  const int tid = threadIdx.x, lane = tid & 63, wv = tid >> 6;
  const int grp = tid >> 4, wq = tid & 15;

  if (blockIdx.x < nbM) {
    // ================= merchant path (pays: account -> merchant) ===========
    const int base = blockIdx.x * 32;
    if (tid < 33) rps1[tid] = rp_p[imin(base + tid, NM)];
    __syncthreads();
    {
      int b0 = rps1[0];
      int lim = imin(rps1[32] - b0, CIS_CAP);
      for (int i = tid; i < lim; i += 256) cis1[i] = ci_p[b0 + i];
    }
    __syncthreads();

    for (int rr = grp; rr < 32; rr += 16) {
      int row = base + rr;
      float s[8] = {0.f, 0.f, 0.f, 0.f, 0.f, 0.f, 0.f, 0.f};
      if (row < NM) grp_gather(rps1, cis1, ci_p, xa, rr, wq, s);
      int deg = rps1[rr + 1] - rps1[rr];
      float rc = (deg > 0) ? 1.f / (float)deg : 0.f;
      int bo = (wq * 16) ^ ((rr & 7) << 4);
      *(uint4*)((char*)&a1[rr][0] + bo) = pack_h8v(s, rc);
    }
    __syncthreads();

    const int rt = wv >> 1, half = wv & 1;
    const int colbase = half * (DOUT / 2);
    const int cn = lane & 15, g = lane >> 4;

    f32x4 acc[NCT];
#pragma unroll
    for (int ct = 0; ct < NCT; ++ct) {
      float b = blP[colbase + ct * 16 + cn];
      acc[ct] = (f32x4){b, b, b, b};
    }

    const int arow = rt * 16 + cn;
    const char* amrow = (const char*)&a1[arow][0];
    const int axor = (arow & 7) << 4;
    const ushort_t* xrow = xm + (size_t)imin(base + arow, NM - 1) * 128;

#pragma unroll
    for (int kt = 0; kt < 4; ++kt) {
      int aoff = (kt * 64 + g * 16) ^ axor;
      h8 a_m = *(const h8*)(amrow + aoff);
      h8 a_x = *(const h8*)((const char*)xrow + kt * 64 + g * 16);
      int nbase = kt * DOUT * 32 + (colbase + cn) * 32 + 8 * g;
#pragma unroll
      for (int ct = 0; ct < NCT; ++ct) {
        int no = nbase + ct * 16 * 32;
        h8 wl = *(const h8*)(WbP + 0 * MB + no);
        h8 wr = *(const h8*)(WbP + 1 * MB + no);
        acc[ct] = __builtin_amdgcn_mfma_f32_16x16x32_f16(a_m, wl, acc[ct], 0, 0, 0);
        acc[ct] = __builtin_amdgcn_mfma_f32_16x16x32_f16(a_x, wr, acc[ct], 0, 0, 0);
      }
    }

    float p[4];
#pragma unroll
    for (int i = 0; i < 4; ++i) {
      float s = 0.f;
#pragma unroll
      for (int ct = 0; ct < NCT; ++ct) s += acc[ct][i] * acc[ct][i];
#pragma unroll
      for (int m = 1; m < 16; m <<= 1) s += __shfl_xor(s, m);
      p[i] = s;
    }
    if (cn == 0) {
#pragma unroll
      for (int i = 0; i < 4; ++i) ssb1[rt * 16 + g * 4 + i][half] = p[i];
    }
    __syncthreads();

#pragma unroll
    for (int i = 0; i < 4; ++i) {
      int rloc = rt * 16 + g * 4 + i;
      int row = base + rloc;
      float ss = ssb1[rloc][0] + ssb1[rloc][1];
      float rn = 1.0f / fmaxf(sqrtf(ss), 1e-12f);
      if (row < NM) {
        ushort_t* op = om + (size_t)row * DOUT + colbase + cn;
#pragma unroll
        for (int ct = 0; ct < NCT; ++ct) op[ct * 16] = f2h(acc[ct][i] * rn);
      }
    }
  } else {
    // ======== account path (rev_pays + transfer, merged) ====================
    const int base = (blockIdx.x - nbM) * 32;
    if (tid < 33) rps1[tid] = rp_r[imin(base + tid, NA)];
    else if (tid < 66) rps2[tid - 33] = rp_t[imin(base + (tid - 33), NA)];
    __syncthreads();
    {
      int b1v = rps1[0];
      int lim1 = imin(rps1[32] - b1v, CIS_CAP);
      for (int i = tid; i < lim1; i += 256) cis1[i] = ci_r[b1v + i];
      int b2v = rps2[0];
      int lim2 = imin(rps2[32] - b2v, CIS_CAP);
      for (int i = tid; i < lim2; i += 256) cis2[i] = ci_t[b2v + i];
    }
    __syncthreads();

    for (int rr = grp; rr < 32; rr += 16) {
      int row = base + rr;
      float s1[8] = {0.f, 0.f, 0.f, 0.f, 0.f, 0.f, 0.f, 0.f};
      float s2[8] = {0.f, 0.f, 0.f, 0.f, 0.f, 0.f, 0.f, 0.f};
      if (row < NA) {
        grp_gather(rps1, cis1, ci_r, xm, rr, wq, s1);
        grp_gather(rps2, cis2, ci_t, xa, rr, wq, s2);
      }
      int d1 = rps1[rr + 1] - rps1[rr];
      int d2 = rps2[rr + 1] - rps2[rr];
      float rc1 = (d1 > 0) ? 1.f / (float)d1 : 0.f;
      float rc2 = (d2 > 0) ? 1.f / (float)d2 : 0.f;
      int bo = (wq * 16) ^ ((rr & 7) << 4);
      *(uint4*)((char*)&a1[rr][0] + bo) = pack_h8v(s1, rc1);
      *(uint4*)((char*)&a2[rr][0] + bo) = pack_h8v(s2, rc2);
    }
    __syncthreads();

    const int rt = wv >> 1, half = wv & 1;
    const int colbase = half * (DOUT / 2);
    const int cn = lane & 15, g = lane >> 4;

    f32x4 acc1[NCT], acc2[NCT];
#pragma unroll
    for (int ct = 0; ct < NCT; ++ct) {
      float b1b = bl1[colbase + ct * 16 + cn];
      float b2b = bl2[colbase + ct * 16 + cn];
      acc1[ct] = (f32x4){b1b, b1b, b1b, b1b};
      acc2[ct] = (f32x4){b2b, b2b, b2b, b2b};
    }

    const int arow = rt * 16 + cn;
    const char* r1p = (const char*)&a1[arow][0];
    const char* r2p = (const char*)&a2[arow][0];
    const int axor = (arow & 7) << 4;
    const ushort_t* xrow = xa + (size_t)imin(base + arow, NA - 1) * 128;

#pragma unroll
    for (int kt = 0; kt < 4; ++kt) {
      int aoff = (kt * 64 + g * 16) ^ axor;
      h8 f1 = *(const h8*)(r1p + aoff);
      h8 f2 = *(const h8*)(r2p + aoff);
      h8 fx = *(const h8*)((const char*)xrow + kt * 64 + g * 16);
      int nbase = kt * DOUT * 32 + (colbase + cn) * 32 + 8 * g;
#pragma unroll
      for (int ct = 0; ct < NCT; ++ct) {
        int no = nbase + ct * 16 * 32;
        h8 wl1 = *(const h8*)(Wb1 + 0 * MB + no);
        h8 wr1 = *(const h8*)(Wb1 + 1 * MB + no);
        h8 wl2 = *(const h8*)(Wb2 + 0 * MB + no);
        h8 wr2 = *(const h8*)(Wb2 + 1 * MB + no);
        acc1[ct] = __builtin_amdgcn_mfma_f32_16x16x32_f16(f1, wl1, acc1[ct], 0, 0, 0);
        acc1[ct] = __builtin_amdgcn_mfma_f32_16x16x32_f16(fx, wr1, acc1[ct], 0, 0, 0);
        acc2[ct] = __builtin_amdgcn_mfma_f32_16x16x32_f16(f2, wl2, acc2[ct], 0, 0, 0);
        acc2[ct] = __builtin_amdgcn_mfma_f32_16x16x32_f16(fx, wr2, acc2[ct], 0, 0, 0);
      }
    }

#pragma unroll
    for (int i = 0; i < 4; ++i) {
      float s1 = 0.f, s2 = 0.f;
#pragma unroll
      for (int ct = 0; ct < NCT; ++ct) {
        s1 += acc1[ct][i] * acc1[ct][i];
        s2 += acc2[ct][i] * acc2[ct][i];
      }
#pragma unroll
      for (int m = 1; m < 16; m <<= 1) {
        s1 += __shfl_xor(s1, m);
        s2 += __shfl_xor(s2, m);
      }
      if (cn == 0) {
        ssb1[rt * 16 + g * 4 + i][half] = s1;
        ssb2[rt * 16 + g * 4 + i][half] = s2;
      }
    }
    __syncthreads();

#pragma unroll
    for (int i = 0; i < 4; ++i) {
      int rloc = rt * 16 + g * 4 + i;
      int row = base + rloc;
      float rn1 = 1.0f / fmaxf(sqrtf(ssb1[rloc][0] + ssb1[rloc][1]), 1e-12f);
      float rn2 = 1.0f / fmaxf(sqrtf(ssb2[rloc][0] + ssb2[rloc][1]), 1e-12f);
      if (row < NA) {
        ushort_t* op = oa + (size_t)row * DOUT + colbase + cn;
#pragma unroll
        for (int ct = 0; ct < NCT; ++ct)
          op[ct * 16] = f2h(acc1[ct][i] * rn1 + acc2[ct][i] * rn2);
      }
    }
  }
}

// ---------------- BN stats (both tensors, one launch) ----------------
template<int C>
__global__ __launch_bounds__(256) void bn_stats2_kernel(
    const ushort_t* __restrict__ xA, float* __restrict__ stA, int nA,
    const ushort_t* __restrict__ xM, float* __restrict__ stM, int nM) {
  constexpr int TPR = C / 8;
  constexpr int RPB = 256 / TPR;
  __shared__ float smw[4][TPR][16];
  int bid = blockIdx.x;
  const ushort_t* x; float* st; int n;
  if (bid < 256) { x = xA; st = stA; n = nA; }
  else { bid -= 256; x = xM; st = stM; n = nM; }
  const int tid = threadIdx.x, lane = tid & 63, wv = tid >> 6;
  const int cg = tid % TPR;
  const int r0 = tid / TPR;

  float s[8] = {0.f, 0.f, 0.f, 0.f, 0.f, 0.f, 0.f, 0.f};
  float q[8] = {0.f, 0.f, 0.f, 0.f, 0.f, 0.f, 0.f, 0.f};
  for (int r = bid * RPB + r0; r < n; r += 256 * RPB) {
    uint4 v = ((const uint4*)(x + (size_t)r * C))[cg];
    unsigned w[4] = {v.x, v.y, v.z, v.w};
#pragma unroll
    for (int j = 0; j < 4; ++j) {
      float a = hlo(w[j]), b = hhi(w[j]);
      s[2 * j] += a; q[2 * j] += a * a;
      s[2 * j + 1] += b; q[2 * j + 1] += b * b;
    }
  }
#pragma unroll
  for (int j = 0; j < 8; ++j) {
    for (int m = TPR; m < 64; m <<= 1) {
      s[j] += __shfl_xor(s[j], m);
      q[j] += __shfl_xor(q[j], m);
    }
  }
  if (lane < TPR) {
#pragma unroll
    for (int j = 0; j < 8; ++j) {
      smw[wv][lane][j] = s[j];
      smw[wv][lane][8 + j] = q[j];
    }
  }
  __syncthreads();
  if (tid < C) {
    int g2 = tid >> 3, j = tid & 7;
    float ts = smw[0][g2][j] + smw[1][g2][j] + smw[2][g2][j] + smw[3][g2][j];
    float tq = smw[0][g2][8 + j] + smw[1][g2][8 + j] + smw[2][g2][8 + j] + smw[3][g2][8 + j];
    atomicAdd(&st[tid], ts);
    atomicAdd(&st[C + tid], tq);
  }
}

// ---------------- BN apply (+ReLU), both tensors, one launch ----------------
template<int C, bool RELU>
__global__ __launch_bounds__(256) void bn_apply2_kernel(
    ushort_t* __restrict__ xA, const float* __restrict__ stA,
    const float* __restrict__ gA, const float* __restrict__ bA, int nA,
    ushort_t* __restrict__ xM, const float* __restrict__ stM,
    const float* __restrict__ gM, const float* __restrict__ bM, int nM) {
  size_t i = (size_t)blockIdx.x * 256 + threadIdx.x;
  size_t totA = (size_t)nA * C / 8;
  ushort_t* x; const float *st, *g, *b; int n;
  if (i < totA) { x = xA; st = stA; g = gA; b = bA; n = nA; }
  else {
    i -= totA;
    size_t totM = (size_t)nM * C / 8;
    if (i >= totM) return;
    x = xM; st = stM; g = gM; b = bM; n = nM;
  }
  int c0 = (int)((i * 8) & (C - 1));
  float rn = 1.f / (float)n;
  uint4 v = ((const uint4*)x)[i];
  unsigned w[4] = {v.x, v.y, v.z, v.w};
  unsigned o[4];
#pragma unroll
  for (int j = 0; j < 4; ++j) {
    int cA = c0 + 2 * j, cB = cA + 1;
    float muA = st[cA] * rn, muB = st[cB] * rn;
    float vaA = st[C + cA] * rn - muA * muA;
    float vaB = st[C + cB] * rn - muB * muB;
    float xAv = (hlo(w[j]) - muA) * rsqrtf(vaA + EPS_BN) * g[cA] + b[cA];
    float xBv = (hhi(w[j]) - muB) * rsqrtf(vaB + EPS_BN) * g[cB] + b[cB];
    if (RELU) { xAv = fmaxf(xAv, 0.f); xBv = fmaxf(xBv, 0.f); }
    o[j] = (unsigned)f2h(xAv) | ((unsigned)f2h(xBv) << 16);
  }
  ((uint4*)x)[i] = make_uint4(o[0], o[1], o[2], o[3]);
}

// ---------------- classifier via MFMA ----------------
__global__ __launch_bounds__(256, 4) void clf_mfma_kernel(
    const ushort_t* __restrict__ X, const ushort_t* __restrict__ WPc,
    const float* __restrict__ b1, const float* __restrict__ W2,
    const float* __restrict__ b2, float* __restrict__ out, int n) {
  __shared__ __align__(16) ushort_t axl[32][64];
  __shared__ float ssb[32][2];
  const int tid = threadIdx.x, lane = tid & 63, wv = tid >> 6;
  const int base = blockIdx.x * 32;

  for (int r = wv; r < 16; r += 4) {
    int rr = 2 * r + (lane >> 5);
    int row = base + rr;
    int el = lane & 31;
    unsigned v = (row < n) ? ((const unsigned*)(X + (size_t)row * 64))[el] : 0u;
    int swz = (rr & 7) << 4;
    *(unsigned*)((char*)&axl[rr][0] + ((4 * el) ^ swz)) = v;
  }
  __syncthreads();

  const int rt = wv >> 1, half = wv & 1;
  const int colbase = half * 32;
  const int cn = lane & 15, g = lane >> 4;

  f32x4 acc[2];
#pragma unroll
  for (int ct = 0; ct < 2; ++ct) {
    float b = b1[colbase + ct * 16 + cn];
    acc[ct] = (f32x4){b, b, b, b};
  }

  const int arow = rt * 16 + cn;
  const char* rowp = (const char*)&axl[arow][0];
  const int swz = (arow & 7) << 4;

#pragma unroll
  for (int kt = 0; kt < 2; ++kt) {
    h8 a = *(const h8*)(rowp + ((kt * 64 + g * 16) ^ swz));
#pragma unroll
    for (int ct = 0; ct < 2; ++ct) {
      int wb = kt * 64 * 32 + (colbase + ct * 16 + cn) * 32 + 8 * g;
      h8 wh = *(const h8*)(WPc + wb);
      acc[ct] = __builtin_amdgcn_mfma_f32_16x16x32_f16(a, wh, acc[ct], 0, 0, 0);
    }
  }

  float w2v0 = W2[colbase + cn], w2v1 = W2[colbase + 16 + cn];
#pragma unroll
  for (int i = 0; i < 4; ++i) {
    float p = fmaxf(acc[0][i], 0.f) * w2v0 + fmaxf(acc[1][i], 0.f) * w2v1;
#pragma unroll
    for (int m = 1; m < 16; m <<= 1) p += __shfl_xor(p, m);
    if (cn == 0) ssb[rt * 16 + g * 4 + i][half] = p;
  }
  __syncthreads();

  if (tid < 32) {
    int row = base + tid;
    if (row < n) out[row] = ssb[tid][0] + ssb[tid][1] + b2[0];
  }
}

// ---------------- one hetero layer (3 dispatches) ----------------
template<int DO, bool RELU>
static void run_layer(const ushort_t* WB, const float* bl,
                      const float* g, const float* b,
                      const ushort_t* xa, const ushort_t* xm,
                      ushort_t* oa, ushort_t* om, float* STATS,
                      const int* rp_p, const int* ci_p,
                      const int* rp_r, const int* ci_r,
                      const int* rp_t, const int* ci_t,
                      int NA, int NM, hipStream_t stream) {
  const size_t ETS = (size_t)8 * DO * 32;
  float* stA = STATS;
  float* stM = STATS + 2 * DO;
  int nbM = idiv(NM, 32), nbA = idiv(NA, 32);
  sage_layer_kernel<DO><<<nbM + nbA, 256, 0, stream>>>(
      nbM, rp_p, ci_p, xa, xm, WB + 0 * ETS, bl, om, NM,
      rp_r, ci_r, rp_t, ci_t, WB + 1 * ETS, WB + 2 * ETS,
      bl + DO, bl + 2 * DO, oa, NA);
  bn_stats2_kernel<DO><<<512, 256, 0, stream>>>(oa, stA, NA, om, stM, NM);
  bn_apply2_kernel<DO, RELU><<<idiv((NA + NM) * DO / 8, 256), 256, 0, stream>>>(
      oa, stA, g, b, NA, om, stM, g + DO, b + DO, NM);
}

static size_t ws_need(int NA, int NM, int E) {
  size_t acts = ((size_t)2 * NA * 128 + (size_t)2 * NM * 128) * 2;
  size_t wbuf = ((size_t)2 * 98304 + 49152 + 8192 + 4096 + 4096) * 2;
  size_t stats = 3 * 1024 * 4;
  size_t ints = ((size_t)(NM + 1) + NM + E
               + 2 * ((size_t)(NA + 1) + NA + E) + 1024) * 4;
  return acts + wbuf + stats + ints + 256;
}

extern "C" void kernel_launch(void* const* d_in, const int* in_sizes, int n_in,
                              void* d_out, int out_size, void* d_ws, size_t ws_size,
                              hipStream_t stream) {
  const int NA = in_sizes[0] / 64;   // 200000
  const int NM = in_sizes[1] / 32;   // 100000
  const int E  = in_sizes[2] / 2;    // 500000
  if (ws_size < ws_need(NA, NM, E)) return;

  const float* x_acc = (const float*)d_in[0];
  const float* x_mer = (const float*)d_in[1];
  const int* ei_pays = (const int*)d_in[2];
  const int* ei_rev  = (const int*)d_in[3];
  const int* ei_tr   = (const int*)d_in[4];
  const float* pWa = (const float*)d_in[5];
  const float* pba = (const float*)d_in[6];
  const float* pWm = (const float*)d_in[7];
  const float* pbm = (const float*)d_in[8];
  const float* Wl[3]  = {(const float*)d_in[9],  (const float*)d_in[12], (const float*)d_in[15]};
  const float* blp[3] = {(const float*)d_in[10], (const float*)d_in[13], (const float*)d_in[16]};
  const float* Wr[3]  = {(const float*)d_in[11], (const float*)d_in[14], (const float*)d_in[17]};
  const float* bng[3] = {(const float*)d_in[18], (const float*)d_in[20], (const float*)d_in[22]};
  const float* bnb[3] = {(const float*)d_in[19], (const float*)d_in[21], (const float*)d_in[23]};
  const float* cW1 = (const float*)d_in[24];
  const float* cb1 = (const float*)d_in[25];
  const float* cW2 = (const float*)d_in[26];
  const float* cb2 = (const float*)d_in[27];

  char* p = (char*)d_ws;
  ushort_t* A0 = (ushort_t*)p; p += (size_t)NA * 128 * 2;
  ushort_t* A1 = (ushort_t*)p; p += (size_t)NA * 128 * 2;
  ushort_t* M0 = (ushort_t*)p; p += (size_t)NM * 128 * 2;
  ushort_t* M1 = (ushort_t*)p; p += (size_t)NM * 128 * 2;
  ushort_t* WB0 = (ushort_t*)p; p += (size_t)98304 * 2;
  ushort_t* WB1 = (ushort_t*)p; p += (size_t)98304 * 2;
  ushort_t* WB2 = (ushort_t*)p; p += (size_t)49152 * 2;
  ushort_t* WPA = (ushort_t*)p; p += (size_t)8192 * 2;
  ushort_t* WPM = (ushort_t*)p; p += (size_t)4096 * 2;
  ushort_t* WPC = (ushort_t*)p; p += (size_t)4096 * 2;
  p = (char*)(((uintptr_t)p + 15) & ~(uintptr_t)15);
  float* STATS = (float*)p; p += 3 * 1024 * 4;
  // cursors contiguous for single memset
  int* cur_p = (int*)p; p += (size_t)NM * 4;
  int* cur_r = (int*)p; p += (size_t)NA * 4;
  int* cur_t = (int*)p; p += (size_t)NA * 4;
  int* rp_p  = (int*)p; p += ((size_t)NM + 1) * 4;
  int* ci_p  = (int*)p; p += (size_t)E * 4;
  int* rp_r  = (int*)p; p += ((size_t)NA + 1) * 4;
  int* ci_r  = (int*)p; p += (size_t)E * 4;
  int* rp_t  = (int*)p; p += ((size_t)NA + 1) * 4;
  int* ci_t  = (int*)p; p += (size_t)E * 4;
  int* bsum  = (int*)p; p += 1024 * 4;

  // ---- CSR builds, batched ----
  hipMemsetAsync(cur_p, 0, ((size_t)NM + 2 * (size_t)NA) * sizeof(int), stream);
  hipMemsetAsync(STATS, 0, 3 * 1024 * sizeof(float), stream);
  int nbPer = idiv(E, 256);
  cnt3_kernel<<<3 * nbPer, 256, 0, stream>>>(ei_pays, cur_p, ei_rev, cur_r,
                                             ei_tr, cur_t, E, nbPer);
  int nb0 = idiv(NM, SCAN_EPB), nb1 = idiv(NA, SCAN_EPB), nb2 = idiv(NA, SCAN_EPB);
  bsum3_kernel<<<nb0 + nb1 + nb2, SCAN_TPB, 0, stream>>>(
      cur_p, NM, cur_r, NA, cur_t, NA, bsum, nb0, nb1);
  bscan3_kernel<<<3, 128, 0, stream>>>(bsum, nb0, nb1, nb2);
  scatter3_kernel<<<nb0 + nb1 + nb2, SCAN_TPB, 0, stream>>>(
      cur_p, rp_p, NM, cur_r, rp_r, NA, cur_t, rp_t, NA, bsum, nb0, nb1, E);
  fill3_kernel<<<3 * nbPer, 256, 0, stream>>>(ei_pays, cur_p, ci_p,
                                              ei_rev, cur_r, ci_r,
                                              ei_tr, cur_t, ci_t, E, nbPer);

  // ---- W conversions (f16) ----
  wprep_kernel<<<idiv(3 * 2 * 128 * 128, 256), 256, 0, stream>>>(Wl[0], Wr[0], WB0, 128);
  wprep_kernel<<<idiv(3 * 2 * 128 * 128, 256), 256, 0, stream>>>(Wl[1], Wr[1], WB1, 128);
  wprep_kernel<<<idiv(3 * 2 * 64 * 128, 256), 256, 0, stream>>>(Wl[2], Wr[2], WB2, 64);
  wprep_one_kernel<<<idiv(128 * 64, 256), 256, 0, stream>>>(pWa, WPA, 128, 64);
  wprep_one_kernel<<<idiv(128 * 32, 256), 256, 0, stream>>>(pWm, WPM, 128, 32);
  wprep_one_kernel<<<idiv(64 * 64, 256), 256, 0, stream>>>(cW1, WPC, 64, 64);

  // ---- input projections (MFMA, f16) ----
  proj_mfma_kernel<64><<<idiv(NA, 32), 256, 0, stream>>>(x_acc, WPA, pba, A0, NA);
  proj_mfma_kernel<32><<<idiv(NM, 32), 256, 0, stream>>>(x_mer, WPM, pbm, M0, NM);

  // ---- 3 hetero layers (3 dispatches each) ----
  ushort_t *xa = A0, *xm = M0, *oa = A1, *om = M1;
  run_layer<128, true>(WB0, blp[0], bng[0], bnb[0], xa, xm, oa, om, STATS,
                       rp_p, ci_p, rp_r, ci_r, rp_t, ci_t, NA, NM, stream);
  { ushort_t* t = xa; xa = oa; oa = t; t = xm; xm = om; om = t; }
  run_layer<128, true>(WB1, blp[1], bng[1], bnb[1], xa, xm, oa, om, STATS + 1024,
                       rp_p, ci_p, rp_r, ci_r, rp_t, ci_t, NA, NM, stream);
  { ushort_t* t = xa; xa = oa; oa = t; t = xm; xm = om; om = t; }
  run_layer<64, false>(WB2, blp[2], bng[2], bnb[2], xa, xm, oa, om, STATS + 2048,
                       rp_p, ci_p, rp_r, ci_r, rp_t, ci_t, NA, NM, stream);
  { ushort_t* t = xa; xa = oa; oa = t; t = xm; xm = om; om = t; }

  // ---- classifier head on accounts (MFMA, f16) ----
  clf_mfma_kernel<<<idiv(NA, 32), 256, 0, stream>>>(xa, WPC, cb1, cW2, cb2,
                                                    (float*)d_out, NA);
}